// Round 8
// baseline (264.892 us; speedup 1.0000x reference)
//
#include <hip/hip_runtime.h>
#include <stdint.h>

// Problem constants
#define ROWS  16384   // B*T
#define CELL  128
#define INF   512
#define RPB   64      // 4 waves x 16 rows
#define NSTEP 32
#define LOG2E 1.4426950408889634f

typedef _Float16 f16x8 __attribute__((ext_vector_type(8)));
typedef _Float16 f16x4 __attribute__((ext_vector_type(4)));
typedef float    f32x4 __attribute__((ext_vector_type(4)));

#define MFMA16(a, b, c) __builtin_amdgcn_mfma_f32_16x16x32_f16((a), (b), (c), 0, 0, 0)

#if __has_builtin(__builtin_amdgcn_exp2f)
#define EXP2(x) __builtin_amdgcn_exp2f(x)
#else
#define EXP2(x) __expf((x) * 0.6931471805599453f)
#endif
#define RCP(x) __builtin_amdgcn_rcpf(x)

// ws layout (f16 units), 16x16x32 A-fragment order A[m=lane&15][k=(lane>>4)*8+j]
// (weights are the A operand of the transposed recurrence z^T = W^T c^T):
//   ws_a: [g<4][mt<8][kt<4][lane][j]   at 0       (65536)   cell part, scaled
//   ws_x: [g<4][mt<8][kt<16][lane][j]  at 65536   (262144)  x part, scaled
//   ws_c: [mt<8][kt<4][lane][j]        at 327680  (16384)   Wc * log2e
//   bias: float[5][128]                at 344064 (f16 units) = byte 688128
// Scales: f,i1,o -> -log2e (sigmoid), i2 -> +2log2e (tanh), Wc/bc -> +log2e.
#define XWOFF 65536
#define WCOFF 327680
#define BOFF  344064
#define PREPN 344704

__device__ __forceinline__ unsigned short f2h_bits(float f) {
  _Float16 h = (_Float16)f;
  return *(unsigned short*)&h;
}

__global__ __launch_bounds__(256) void prep_kernel(
    const float* __restrict__ Wf, const float* __restrict__ Wi1,
    const float* __restrict__ Wi2, const float* __restrict__ Wo,
    const float* __restrict__ Wc,
    const float* __restrict__ bf_, const float* __restrict__ bi1,
    const float* __restrict__ bi2, const float* __restrict__ bo,
    const float* __restrict__ bc, unsigned short* __restrict__ ws) {
  int id = blockIdx.x * blockDim.x + threadIdx.x;
  if (id >= PREPN) return;
  const float* Wg[4] = {Wf, Wi1, Wi2, Wo};
  const float sc[4] = {-LOG2E, -LOG2E, 2.f * LOG2E, -LOG2E};
  if (id < XWOFF) {                      // cell part
    int j = id & 7, lane = (id >> 3) & 63, kt = (id >> 9) & 3,
        mt = (id >> 11) & 7, g = id >> 14;
    int cin = kt * 32 + ((lane >> 4) << 3) + j;
    int cout = mt * 16 + (lane & 15);
    ws[id] = f2h_bits(Wg[g][cin * CELL + cout] * sc[g]);
  } else if (id < WCOFF) {               // x part (W rows 128..639)
    int t = id - XWOFF;
    int j = t & 7, lane = (t >> 3) & 63, kt = (t >> 9) & 15,
        mt = (t >> 13) & 7, g = t >> 16;
    int xf = kt * 32 + ((lane >> 4) << 3) + j;
    int cout = mt * 16 + (lane & 15);
    ws[id] = f2h_bits(Wg[g][(CELL + xf) * CELL + cout] * sc[g]);
  } else if (id < BOFF) {                // Wc
    int r = id - WCOFF;
    int j = r & 7, lane = (r >> 3) & 63, kt = (r >> 9) & 3, mt = (r >> 11) & 7;
    int cin = kt * 32 + ((lane >> 4) << 3) + j;
    int cout = mt * 16 + (lane & 15);
    ws[id] = f2h_bits(Wc[cin * CELL + cout] * LOG2E);
  } else {                               // biases as f32
    int i = id - BOFF;
    int g = i >> 7, cell = i & 127;
    float v;
    if (g == 0) v = bf_[cell] * (-LOG2E);
    else if (g == 1) v = bi1[cell] * (-LOG2E);
    else if (g == 2) v = bi2[cell] * (2.f * LOG2E);
    else if (g == 3) v = bo[cell] * (-LOG2E);
    else v = bc[cell] * LOG2E;
    ((float*)(ws + BOFF))[i] = v;
  }
}

// Barrier-free recurrence: 1 block/CU (grid 256), 1 wave/SIMD, each wave owns
// 16 rows x all 128 cols. Recurrent weights (3 gates) in 384 regs (VGPR+AGPR
// unified). c round-trips through wave-private LDS (in-order DS, lgkmcnt only,
// no __syncthreads after the precompute phase).
__global__ __launch_bounds__(256, 1) void lstm_kernel(
    const float* __restrict__ x,
    const unsigned short* __restrict__ ws, float* __restrict__ out) {

  __shared__ union {
    _Float16 xs[64 * 512];            // staging: row*512 + swz_gran*8 (64 KB)
    _Float16 u4[4 * 4 * 8 * 64 * 4];  // [wv][g][mt][lane][4] f16 (64 KB)
  } uS;
  __shared__ _Float16 cbuf[4 * 2 * 16 * 128];  // [wv][buf][row16][swizzled] 32 KB

  const int tid  = threadIdx.x;
  const int lane = tid & 63;
  const int wv   = tid >> 6;
  const int n16  = lane & 15;          // this lane's row within the wave
  const int q    = lane >> 4;          // k-group / D-row-quad
  const int r0   = blockIdx.x * RPB;
  const int myrow = wv * 16 + n16;     // row within block

  const _Float16* W = (const _Float16*)ws;
  const float* biasf = (const float*)(ws + BOFF);

  // ---------------- stage x -> LDS f16 (16B granules, XOR-swizzled) -------
#pragma unroll
  for (int i = 0; i < 16; ++i) {
    int flat = tid + i * 256;          // 4096 = 64 rows * 64 granules
    int row = flat >> 6, g = flat & 63;
    int gs = g ^ (row & 15);
    const float* src = x + (size_t)(r0 + row) * INF + g * 8;
    float4 v0 = *(const float4*)src;
    float4 v1 = *(const float4*)(src + 4);
    f16x8 h = {(_Float16)v0.x, (_Float16)v0.y, (_Float16)v0.z, (_Float16)v0.w,
               (_Float16)v1.x, (_Float16)v1.y, (_Float16)v1.z, (_Float16)v1.w};
    *(f16x8*)&uS.xs[row * 512 + gs * 8] = h;
  }
  __syncthreads();

  // ---------------- precompute u^T = Wx^T @ x^T (per wave, all 4 gates) ---
  f32x4 acc[4][8];
#pragma unroll
  for (int g = 0; g < 4; ++g)
#pragma unroll
    for (int mt = 0; mt < 8; ++mt) acc[g][mt] = (f32x4){0.f, 0.f, 0.f, 0.f};

  {
    const int xbase = myrow * 512;
#pragma unroll 1
    for (int kt = 0; kt < 16; ++kt) {
      f16x8 b = *(const f16x8*)&uS.xs[xbase + (((kt * 4 + q) ^ n16) << 3)];
#pragma unroll
      for (int g = 0; g < 4; ++g)
#pragma unroll
        for (int mt = 0; mt < 8; ++mt) {
          f16x8 a = *(const f16x8*)&W[XWOFF + (((g * 8 + mt) * 16 + kt) << 9) + lane * 8];
          acc[g][mt] = MFMA16(a, b, acc[g][mt]);
        }
    }
  }
  __syncthreads();   // all waves done reading xs; u4 region becomes live

  // biases + write u (f16) to wave-private LDS
#pragma unroll
  for (int g = 0; g < 4; ++g)
#pragma unroll
    for (int mt = 0; mt < 8; ++mt) {
      float4 bv = *(const float4*)(biasf + g * 128 + mt * 16 + q * 4);
      acc[g][mt][0] += bv.x; acc[g][mt][1] += bv.y;
      acc[g][mt][2] += bv.z; acc[g][mt][3] += bv.w;
      f16x4 h = {(_Float16)acc[g][mt][0], (_Float16)acc[g][mt][1],
                 (_Float16)acc[g][mt][2], (_Float16)acc[g][mt][3]};
      *(f16x4*)&uS.u4[(((wv * 4 + g) * 8 + mt) << 8) + lane * 4] = h;
    }

  // ---------------- step 0: c0 = sig(u_i1)*tanh(u_i2) ---------------------
  const int cb = wv * 4096 + n16 * 128;          // this wave+row's cbuf base
  int rdo[4], wro[8];
#pragma unroll
  for (int kt = 0; kt < 4; ++kt) rdo[kt] = cb + (((kt * 4 + q) ^ n16) << 3);
#pragma unroll
  for (int mt = 0; mt < 8; ++mt)
    wro[mt] = cb + (((mt * 2 + (q >> 1)) ^ n16) << 3) + (q & 1) * 4;

  f32x4 cr[8];
#pragma unroll
  for (int mt = 0; mt < 8; ++mt) {
#pragma unroll
    for (int r = 0; r < 4; ++r) {
      float ei = EXP2(fminf(acc[1][mt][r], 30.f));
      float eg = EXP2(fminf(acc[2][mt][r], 30.f));
      cr[mt][r] = (eg - 1.f) * RCP((1.f + ei) * (1.f + eg));
    }
    f16x4 h = {(_Float16)cr[mt][0], (_Float16)cr[mt][1],
               (_Float16)cr[mt][2], (_Float16)cr[mt][3]};
    *(f16x4*)&cbuf[wro[mt]] = h;                  // buf 0
  }
#if __has_builtin(__builtin_amdgcn_sched_barrier)
  __builtin_amdgcn_sched_barrier(0);   // keep W loads after acc[] dies
#endif

  // ---------------- recurrent weights -> 384 regs -------------------------
  f16x8 wr[3][8][4];
#pragma unroll
  for (int g = 0; g < 3; ++g)
#pragma unroll
    for (int mt = 0; mt < 8; ++mt)
#pragma unroll
      for (int kt = 0; kt < 4; ++kt)
        wr[g][mt][kt] = *(const f16x8*)&W[(((g * 8 + mt) * 4 + kt) << 9) + lane * 8];

  const int ub = (wv * 4) * 2048;      // u4 base for this wave (f16 units)

  // ---------------- recurrence: steps 1..30 (NO barriers) -----------------
#pragma unroll 1
  for (int t = 1; t < NSTEP - 1; ++t) {
    const int rb = ((t + 1) & 1) * 2048, wb = (t & 1) * 2048;
    f16x8 b[4];
#pragma unroll
    for (int kt = 0; kt < 4; ++kt) b[kt] = *(const f16x8*)&cbuf[rdo[kt] + rb];
#pragma unroll
    for (int mt = 0; mt < 8; ++mt) {
      f16x4 u0 = *(const f16x4*)&uS.u4[ub + (mt << 8) + lane * 4];
      f16x4 u1 = *(const f16x4*)&uS.u4[ub + 2048 + (mt << 8) + lane * 4];
      f16x4 u2 = *(const f16x4*)&uS.u4[ub + 4096 + (mt << 8) + lane * 4];
      f32x4 zf  = {(float)u0[0], (float)u0[1], (float)u0[2], (float)u0[3]};
      f32x4 zi1 = {(float)u1[0], (float)u1[1], (float)u1[2], (float)u1[3]};
      f32x4 zi2 = {(float)u2[0], (float)u2[1], (float)u2[2], (float)u2[3]};
#pragma unroll
      for (int kt = 0; kt < 4; ++kt) {
        zf  = MFMA16(wr[0][mt][kt], b[kt], zf);
        zi1 = MFMA16(wr[1][mt][kt], b[kt], zi1);
        zi2 = MFMA16(wr[2][mt][kt], b[kt], zi2);
      }
#pragma unroll
      for (int r = 0; r < 4; ++r) {
        float ef = EXP2(fminf(zf[r],  30.f));
        float ei = EXP2(fminf(zi1[r], 30.f));
        float eg = EXP2(fminf(zi2[r], 30.f));
        float fp1 = 1.f + ef;
        float p   = (1.f + ei) * (1.f + eg);
        cr[mt][r] = fmaf(cr[mt][r], p, fp1 * (eg - 1.f)) * RCP(fp1 * p);
      }
      f16x4 h = {(_Float16)cr[mt][0], (_Float16)cr[mt][1],
                 (_Float16)cr[mt][2], (_Float16)cr[mt][3]};
      *(f16x4*)&cbuf[wro[mt] + wb] = h;
    }
  }

  // ---------------- final step (t=31): + o-gate, o -> cbuf buf1 -----------
  {
    f16x8 b[4];
#pragma unroll
    for (int kt = 0; kt < 4; ++kt) b[kt] = *(const f16x8*)&cbuf[rdo[kt]]; // buf0
#pragma unroll
    for (int mt = 0; mt < 8; ++mt) {
      f16x4 u0 = *(const f16x4*)&uS.u4[ub + (mt << 8) + lane * 4];
      f16x4 u1 = *(const f16x4*)&uS.u4[ub + 2048 + (mt << 8) + lane * 4];
      f16x4 u2 = *(const f16x4*)&uS.u4[ub + 4096 + (mt << 8) + lane * 4];
      f16x4 u3 = *(const f16x4*)&uS.u4[ub + 6144 + (mt << 8) + lane * 4];
      f32x4 zf  = {(float)u0[0], (float)u0[1], (float)u0[2], (float)u0[3]};
      f32x4 zi1 = {(float)u1[0], (float)u1[1], (float)u1[2], (float)u1[3]};
      f32x4 zi2 = {(float)u2[0], (float)u2[1], (float)u2[2], (float)u2[3]};
      f32x4 zo  = {(float)u3[0], (float)u3[1], (float)u3[2], (float)u3[3]};
#pragma unroll
      for (int kt = 0; kt < 4; ++kt) {
        f16x8 wof = *(const f16x8*)&W[(((3 * 8 + mt) * 4 + kt) << 9) + lane * 8];
        zf  = MFMA16(wr[0][mt][kt], b[kt], zf);
        zi1 = MFMA16(wr[1][mt][kt], b[kt], zi1);
        zi2 = MFMA16(wr[2][mt][kt], b[kt], zi2);
        zo  = MFMA16(wof, b[kt], zo);
      }
      f16x4 h;
#pragma unroll
      for (int r = 0; r < 4; ++r) {
        float ef = EXP2(fminf(zf[r],  30.f));
        float ei = EXP2(fminf(zi1[r], 30.f));
        float eg = EXP2(fminf(zi2[r], 30.f));
        float fp1 = 1.f + ef;
        float p   = (1.f + ei) * (1.f + eg);
        float cn  = fmaf(cr[mt][r], p, fp1 * (eg - 1.f)) * RCP(fp1 * p);
        cr[mt][r] = cn;
        float eo = EXP2(fminf(zo[r], 30.f));
        float ec = EXP2(fminf(cn * (2.f * LOG2E), 30.f));
        h[r] = (_Float16)((ec - 1.f) * RCP((1.f + eo) * (1.f + ec)));
      }
      *(f16x4*)&cbuf[wro[mt] + 2048] = h;        // o into buf 1
    }
  }

  // ---------------- epilogue: s^T = Wc^T @ o^T, softmax, stores -----------
  {
    f16x8 ob[4];
#pragma unroll
    for (int kt = 0; kt < 4; ++kt) ob[kt] = *(const f16x8*)&cbuf[rdo[kt] + 2048];
    f32x4 sa[8];
#pragma unroll
    for (int mt = 0; mt < 8; ++mt) {
      float4 bv = *(const float4*)(biasf + 4 * 128 + mt * 16 + q * 4);
      sa[mt] = (f32x4){bv.x, bv.y, bv.z, bv.w};
#pragma unroll
      for (int kt = 0; kt < 4; ++kt) {
        f16x8 a = *(const f16x8*)&W[WCOFF + ((mt * 4 + kt) << 9) + lane * 8];
        sa[mt] = MFMA16(a, ob[kt], sa[mt]);
      }
    }
    // softmax over the 128 cells of this lane's row: local 32 + lanes {^16,^32}
    float m = -1e30f;
#pragma unroll
    for (int mt = 0; mt < 8; ++mt)
#pragma unroll
      for (int r = 0; r < 4; ++r) m = fmaxf(m, sa[mt][r]);
    m = fmaxf(m, __shfl_xor(m, 16, 64));
    m = fmaxf(m, __shfl_xor(m, 32, 64));
    float sm = 0.f;
    float ev[8][4];
#pragma unroll
    for (int mt = 0; mt < 8; ++mt)
#pragma unroll
      for (int r = 0; r < 4; ++r) { ev[mt][r] = EXP2(sa[mt][r] - m); sm += ev[mt][r]; }
    sm += __shfl_xor(sm, 16, 64);
    sm += __shfl_xor(sm, 32, 64);
    float inv = RCP(sm);

    size_t obase = (size_t)(r0 + myrow) * 128;
#pragma unroll
    for (int mt = 0; mt < 8; ++mt) {
      float4 p = {ev[mt][0] * inv, ev[mt][1] * inv, ev[mt][2] * inv, ev[mt][3] * inv};
      *(float4*)&out[obase + mt * 16 + q * 4] = p;
    }
#pragma unroll
    for (int mt = 0; mt < 8; ++mt) {
      float4 p = {cr[mt][0], cr[mt][1], cr[mt][2], cr[mt][3]};
      *(float4*)&out[(size_t)ROWS * 128 + obase + mt * 16 + q * 4] = p;
    }
  }
}

extern "C" void kernel_launch(void* const* d_in, const int* in_sizes, int n_in,
                              void* d_out, int out_size, void* d_ws, size_t ws_size,
                              hipStream_t stream) {
  const float* x   = (const float*)d_in[0];
  const float* Wf  = (const float*)d_in[1];
  const float* bf_ = (const float*)d_in[2];
  const float* Wi1 = (const float*)d_in[3];
  const float* bi1 = (const float*)d_in[4];
  const float* Wi2 = (const float*)d_in[5];
  const float* bi2 = (const float*)d_in[6];
  const float* Wo  = (const float*)d_in[7];
  const float* bo  = (const float*)d_in[8];
  const float* Wc  = (const float*)d_in[9];
  const float* bc  = (const float*)d_in[10];
  unsigned short* ws = (unsigned short*)d_ws;
  float* out = (float*)d_out;

  hipLaunchKernelGGL(prep_kernel, dim3((PREPN + 255) / 256), dim3(256), 0, stream,
                     Wf, Wi1, Wi2, Wo, Wc, bf_, bi1, bi2, bo, bc, ws);
  hipLaunchKernelGGL(lstm_kernel, dim3(ROWS / RPB), dim3(256), 0, stream,
                     x, ws, out);
}